// Round 2
// baseline (39597.342 us; speedup 1.0000x reference)
//
#include <hip/hip_runtime.h>
#include <math.h>

#pragma clang fp contract(off)

#define DD 384
#define NS 96

// A = I - P P^T, upper triangle only (P = eigfunc[:, :NS], rows of eigfunc are contiguous)
__global__ void build_A_kernel(const float* __restrict__ eig, float* __restrict__ A) {
    int idx = blockIdx.x * blockDim.x + threadIdx.x;
    if (idx >= DD * DD) return;
    int j = idx / DD, z = idx - j * DD;
    if (z < j) return;
    const float* rj = eig + (size_t)j * DD;
    const float* rz = eig + (size_t)z * DD;
    float s = 0.0f;
    for (int c = 0; c < NS; ++c) s = fmaf(rj[c], rz[c], s);
    A[(size_t)j * DD + z] = ((j == z) ? 1.0f : 0.0f) - s;
}

// Single persistent workgroup: 96 sequential sampling steps.
// A = committed Schur state (eliminated through xbase-1, upper triangle).
// W = speculative copy for pivot scan of the current step.
__global__ __launch_bounds__(1024) void sampler_kernel(const float* __restrict__ u,
                                                       float* __restrict__ A,
                                                       float* __restrict__ W,
                                                       float* __restrict__ out) {
    __shared__ float pivL[DD];
    __shared__ float vec[DD];
    __shared__ float probs[DD];
    __shared__ float s_inv;
    __shared__ int s_pos;

    const int t = threadIdx.x;
    const int trow = t >> 5;   // 0..31
    const int tcol = t & 31;   // 0..31

    int xbase = 0;
    for (int k = 0; k < NS; ++k) {
        const int xmax = DD - NS + k + 1;
        const int n0 = xmax - xbase;

        // ---- copy upper-tri region [xbase,xmax)^2 from A into W ----
        for (int yr = trow; yr < n0; yr += 32) {
            const float* ap = A + (size_t)(xbase + yr) * DD + xbase;
            float* wp = W + (size_t)(xbase + yr) * DD + xbase;
            for (int zr = yr + tcol; zr < n0; zr += 32) wp[zr] = ap[zr];
        }
        __syncthreads();

        // ---- speculative eliminations, recording pivots for [xbase, xmax) ----
        for (int x = xbase; x < xmax; ++x) {
            const int m = xmax - 1 - x;  // active rows/cols x+1..xmax-1
            if (t == 0) {
                float p = W[(size_t)x * DD + x];
                pivL[x] = p;
                s_inv = (fabsf(p) > 1e-30f) ? (1.0f / p) : 0.0f;
            }
            // stage row x (== col x by symmetry)
            for (int i = t; i < m; i += 1024) vec[i] = W[(size_t)x * DD + (x + 1 + i)];
            __syncthreads();
            if (m > 0) {
                const float inv = s_inv;
                for (int yr = trow; yr < m; yr += 32) {
                    float* wp = W + (size_t)(x + 1 + yr) * DD + (x + 1);
                    const float cy = vec[yr];
                    for (int zr = yr + tcol; zr < m; zr += 32) {
                        float c = inv * (cy * vec[zr]);   // mimic: inv * (a*b), then subtract
                        wp[zr] = wp[zr] - c;
                    }
                }
            }
            __syncthreads();
        }

        // ---- sampling: exact sequential mimic of the reference ----
        if (t == 0) {
            float cp = 1.0f;
            for (int x = 0; x < DD; ++x) {
                float pr = 0.0f;
                if (x >= xbase && x < xmax) {
                    const float p = pivL[x];
                    pr = cp * (1.0f - p);
                    if (!(fabsf(pr) > 1e-15f)) pr = 0.0f;
                    cp = cp * p;
                }
                probs[x] = pr;
            }
            float tot = 0.0f;
            for (int x = 0; x < DD; ++x) tot += probs[x];
            const float target = u[k] * tot;
            int cnt = 0;
            float run = 0.0f;
            for (int x = 0; x < DD; ++x) {
                run += probs[x];
                if (run < target) ++cnt;
            }
            int pos = cnt < (xmax - 1) ? cnt : (xmax - 1);
            s_pos = pos;
            out[k] = (float)pos;       // positions as exact float ints
            out[NS + k] = probs[pos];  // cond_probs
        }
        __syncthreads();
        const int pos = s_pos;

        // ---- commit eliminations xbase..pos on A (full trailing range) ----
        for (int x = xbase; x <= pos; ++x) {
            const int m = DD - 1 - x;
            if (t == 0) {
                float p = A[(size_t)x * DD + x];
                if (x == pos) { p = p - 1.0f; A[(size_t)x * DD + x] = p; }  // occ[pos] = 1
                s_inv = (fabsf(p) > 1e-30f) ? (1.0f / p) : 0.0f;
            }
            for (int i = t; i < m; i += 1024) vec[i] = A[(size_t)x * DD + (x + 1 + i)];
            __syncthreads();
            if (m > 0) {
                const float inv = s_inv;
                for (int yr = trow; yr < m; yr += 32) {
                    float* ap = A + (size_t)(x + 1 + yr) * DD + (x + 1);
                    const float cy = vec[yr];
                    for (int zr = yr + tcol; zr < m; zr += 32) {
                        float c = inv * (cy * vec[zr]);
                        ap[zr] = ap[zr] - c;
                    }
                }
            }
            __syncthreads();
        }
        xbase = pos + 1;
    }
}

extern "C" void kernel_launch(void* const* d_in, const int* in_sizes, int n_in,
                              void* d_out, int out_size, void* d_ws, size_t ws_size,
                              hipStream_t stream) {
    const float* eig = (const float*)d_in[0];
    const float* u   = (const float*)d_in[1];
    float* out = (float*)d_out;
    float* A = (float*)d_ws;                    // 384*384 floats (upper tri used)
    float* W = A + (size_t)DD * DD;             // 384*384 floats (upper tri used)
    build_A_kernel<<<(DD * DD + 255) / 256, 256, 0, stream>>>(eig, A);
    sampler_kernel<<<1, 1024, 0, stream>>>(u, A, W, out);
}

// Round 3
// 36639.798 us; speedup vs baseline: 1.0807x; 1.0807x over previous
//
#include <hip/hip_runtime.h>
#include <math.h>

#pragma clang fp contract(off)

#define DD 384
#define NS 96
#define PB 32     // panel width (pivots per panel)
#define PW 388    // panel row stride (floats), >= 384, 16B-aligned rows
#define NW 16     // waves per block

// A = I - P P^T, full symmetric matrix (P = eigfunc[:, :NS])
__global__ void build_A_kernel(const float* __restrict__ eig, float* __restrict__ A) {
    int idx = blockIdx.x * blockDim.x + threadIdx.x;
    if (idx >= DD * DD) return;
    int j = idx / DD, z = idx - j * DD;
    const float* rj = eig + (size_t)j * DD;
    const float* rz = eig + (size_t)z * DD;
    float s = 0.0f;
    for (int c = 0; c < NS; ++c) s = fmaf(rj[c], rz[c], s);
    A[(size_t)j * DD + z] = ((j == z) ? 1.0f : 0.0f) - s;
}

__global__ __launch_bounds__(1024) void sampler_kernel(const float* __restrict__ u,
                                                       float* __restrict__ A,
                                                       float* __restrict__ W,
                                                       float* __restrict__ out) {
    __shared__ float sp[PB * PW];   // panel rows (LDS), row i = global row x0+i, col j = global col x0+j
    __shared__ float sinv[PB];
    __shared__ float pivL[DD];
    __shared__ float probs[DD];
    __shared__ int s_pos;

    const int t = threadIdx.x;
    const int wid = t >> 6;
    const int lane = t & 63;
    const int lr = lane >> 4;   // 0..3  (row group in trailing tile)
    const int lc = lane & 15;   // 0..15 (col group in trailing tile)

    // Blocked phase: pivots [px0, pend), columns [px0, cmax). Bit-exact vs the
    // per-pivot rank-1 reference: every element receives c_i = inv_i*(cy_i*cz_i)
    // subtractions in ascending pivot order with identical parenthesization.
    auto do_panels = [&](const float* SRC0, float* DST, int px0, int pend, int cmax, int posAdj) {
        for (int x0 = px0; x0 < pend; x0 += PB) {
            const int rem = pend - x0;
            const int bs = (rem < PB) ? rem : PB;
            const int width = cmax - x0;
            const float* SRC = (x0 == px0) ? SRC0 : DST;

            // ---- load panel rows: row i, cols [i, width) ----
            for (int i = wid; i < bs; i += NW) {
                const float* srow = SRC + (size_t)(x0 + i) * DD + x0;
                for (int j = i + lane; j < width; j += 64)
                    sp[i * PW + j] = srow[j];
            }
            __syncthreads();

            // ---- wave0: left-looking panel factorization (no barriers needed) ----
            if (wid == 0) {
                {
                    float p = sp[0];
                    if (x0 == posAdj) p = p - 1.0f;
                    float inv = (fabsf(p) > 1e-30f) ? (1.0f / p) : 0.0f;
                    if (lane == 0) { pivL[x0] = p; sinv[0] = inv; }
                }
                for (int r = 1; r < bs; ++r) {
                    for (int j = r + lane; j < width; j += 64) {
                        float w = sp[r * PW + j];
                        for (int i = 0; i < r; ++i) {
                            float c = sinv[i] * (sp[i * PW + r] * sp[i * PW + j]);
                            w = w - c;
                        }
                        sp[r * PW + j] = w;
                    }
                    float p = sp[r * PW + r];
                    if ((x0 + r) == posAdj) p = p - 1.0f;
                    float inv = (fabsf(p) > 1e-30f) ? (1.0f / p) : 0.0f;
                    if (lane == 0) { pivL[x0 + r] = p; sinv[r] = inv; }
                }
            }
            __syncthreads();

            // ---- trailing update: rows [x0+bs, cmax), cols [y, cmax), rank-bs ----
            const int tb = x0 + bs;
            if (tb < cmax) {
                int tile = 0;
                for (int ty = tb; ty < cmax; ty += 16) {
                    for (int tz = ty; tz < cmax; tz += 64) {
                        if ((tile++ & (NW - 1)) != wid) continue;
                        const int ybase = ty + 4 * lr;
                        const int zbase = tz + lc;
                        float wv[4][4];
                        const bool fast = (tz != ty) && (ty + 16 <= cmax) && (tz + 64 <= cmax);
                        if (fast) {
                            #pragma unroll
                            for (int yi = 0; yi < 4; ++yi) {
                                const float* srow = SRC + (size_t)(ybase + yi) * DD;
                                #pragma unroll
                                for (int zi = 0; zi < 4; ++zi)
                                    wv[yi][zi] = srow[zbase + 16 * zi];
                            }
                            for (int b = 0; b < bs; ++b) {
                                const float inv = sinv[b];
                                float cy[4], cz[4];
                                #pragma unroll
                                for (int yi = 0; yi < 4; ++yi) cy[yi] = sp[b * PW + (ybase + yi - x0)];
                                #pragma unroll
                                for (int zi = 0; zi < 4; ++zi) cz[zi] = sp[b * PW + (zbase + 16 * zi - x0)];
                                #pragma unroll
                                for (int yi = 0; yi < 4; ++yi) {
                                    #pragma unroll
                                    for (int zi = 0; zi < 4; ++zi) {
                                        float c = inv * (cy[yi] * cz[zi]);
                                        wv[yi][zi] = wv[yi][zi] - c;
                                    }
                                }
                            }
                            #pragma unroll
                            for (int yi = 0; yi < 4; ++yi) {
                                float* drow = DST + (size_t)(ybase + yi) * DD;
                                #pragma unroll
                                for (int zi = 0; zi < 4; ++zi)
                                    drow[zbase + 16 * zi] = wv[yi][zi];
                            }
                        } else {
                            // masked edge/diagonal tile
                            #pragma unroll
                            for (int yi = 0; yi < 4; ++yi) {
                                const int y = ybase + yi;
                                #pragma unroll
                                for (int zi = 0; zi < 4; ++zi) {
                                    const int z = zbase + 16 * zi;
                                    float v = 0.0f;
                                    if (y < cmax && z < cmax && z >= y) v = SRC[(size_t)y * DD + z];
                                    wv[yi][zi] = v;
                                }
                            }
                            for (int b = 0; b < bs; ++b) {
                                const float inv = sinv[b];
                                #pragma unroll
                                for (int yi = 0; yi < 4; ++yi) {
                                    const int y = ybase + yi;
                                    const int yy = (y < cmax) ? (y - x0) : 0;   // clamped LDS index
                                    const float cy = sp[b * PW + yy];
                                    #pragma unroll
                                    for (int zi = 0; zi < 4; ++zi) {
                                        const int z = zbase + 16 * zi;
                                        const int zz = (z < cmax) ? (z - x0) : 0;
                                        const float cz = sp[b * PW + zz];
                                        float c = inv * (cy * cz);
                                        wv[yi][zi] = wv[yi][zi] - c;
                                    }
                                }
                            }
                            #pragma unroll
                            for (int yi = 0; yi < 4; ++yi) {
                                const int y = ybase + yi;
                                #pragma unroll
                                for (int zi = 0; zi < 4; ++zi) {
                                    const int z = zbase + 16 * zi;
                                    if (y < cmax && z < cmax && z >= y)
                                        DST[(size_t)y * DD + z] = wv[yi][zi];
                                }
                            }
                        }
                    }
                }
            }
            __syncthreads();
        }
    };

    int xbase = 0;
    for (int k = 0; k < NS; ++k) {
        const int xmax = DD - NS + k + 1;

        // ---- speculative phase: pivots for [xbase, xmax), columns < xmax, A -> W ----
        do_panels(A, W, xbase, xmax, xmax, -1);

        // ---- sampling: sequential scalar, bit-faithful to reference ----
        if (t == 0) {
            float cp = 1.0f;
            float tot = 0.0f;
            for (int x = xbase; x < xmax; ++x) {
                const float p = pivL[x];
                float pr = cp * (1.0f - p);
                if (!(fabsf(pr) > 1e-15f)) pr = 0.0f;
                probs[x] = pr;
                tot = tot + pr;
                cp = cp * p;
            }
            const float uk = u[k];
            const float target = uk * tot;
            int cnt = (target > 0.0f) ? xbase : 0;   // zeros below window: 0 < target
            float run = 0.0f;
            for (int x = xbase; x < xmax; ++x) {
                run = run + probs[x];
                if (run < target) ++cnt;
            }
            if (tot < target) cnt += DD - xmax;      // zeros above window: tot < target
            int pos = (cnt < xmax - 1) ? cnt : (xmax - 1);
            s_pos = pos;
            out[k] = (float)pos;
            out[NS + k] = (pos >= xbase) ? probs[pos] : 0.0f;
        }
        __syncthreads();
        const int pos = s_pos;

        // ---- commit phase: pivots xbase..pos, full width, in-place on A ----
        do_panels(A, A, xbase, pos + 1, DD, pos);

        xbase = pos + 1;
    }
}

extern "C" void kernel_launch(void* const* d_in, const int* in_sizes, int n_in,
                              void* d_out, int out_size, void* d_ws, size_t ws_size,
                              hipStream_t stream) {
    const float* eig = (const float*)d_in[0];
    const float* u   = (const float*)d_in[1];
    float* out = (float*)d_out;
    float* A = (float*)d_ws;
    float* W = A + (size_t)DD * DD;
    build_A_kernel<<<(DD * DD + 255) / 256, 256, 0, stream>>>(eig, A);
    sampler_kernel<<<1, 1024, 0, stream>>>(u, A, W, out);
}